// Round 12
// baseline (260.312 us; speedup 1.0000x reference)
//
#include <hip/hip_runtime.h>
#include <cstdint>
#include <cstddef>

typedef unsigned short u16;
typedef __attribute__((ext_vector_type(8))) short short8;
typedef __attribute__((ext_vector_type(4))) float f32x4;

#define BB 4
#define SS 2048
#define DD 1024

__device__ __forceinline__ u16 f2bf(float f) {
  union { float f; unsigned u; } x; x.f = f;
  unsigned r = x.u + 0x7FFFu + ((x.u >> 16) & 1u);
  return (u16)(r >> 16);
}

__device__ __forceinline__ void gld_lds16(const void* g, void* l) {
  __builtin_amdgcn_global_load_lds(
      (const __attribute__((address_space(1))) void*)g,
      (__attribute__((address_space(3))) void*)l, 16, 0, 0);
}

__device__ __forceinline__ void store_out(float* p, float v) { *p = v; }
__device__ __forceinline__ void store_out(u16* p, float v) { *p = f2bf(v); }

// ---------------------------------------------------------------------------
// 4-WAVE (256-thread) 3-slot-ring GEMM, 128x256 tile, BK=32/slot,
// waves 2M x 2N -> per-wave tile 64x128, acc[4][8] = 128 regs.
// WHY 4 waves (r11 lesson): occupancy math must count VGPR+AGPR UNIFIED.
// 8-wave blocks at 152 regs/wave can never fit 4 waves/SIMD (needs <=128)
// -> no partner block -> barrier convoy exposed (r9/r11 plateau at 33%).
// 4-wave blocks: 2 blocks/CU = 2 waves/SIMD x ~200 regs = 400 <= 512 pool,
// LDS 2 x 72 KB <= 160 KB -> two INDEPENDENT barrier domains per SIMD
// overlap each other's stalls (m114). Also 64x128 wave tile cuts the
// per-CU LDS-read wall to 1152 cyc/K-tile64 (< MFMA 1242) vs r9's 1536.
// Phase p: vmcnt(6) [forces slot p staged at p-2; newest slot's 6 loads
// stay in flight -- never 0 mid-loop]; s_barrier; sched_barrier;
// read A(4)+B(8) b128 frags; STAGE slot p+2 (6 gld_lds);
// setprio(1) 32 MFMA setprio(0).
// WAR: STAGE(p+2) writes slot (p-1)%3; all waves' reads of it completed
// before their MMA(p-1) issue, which precedes barrier(p).
// LDS swizzle (both-sides involution, 0 conflicts): cbyte ^= ((row>>1)&3)<<4.
// MODE 0: C[row][col] = acc*scale (+bias[col]).
// MODE 1 (QKV): colg<1024 -> C (Q), <2048 -> out2 (K); V blocks
// (blockN>=2048) use operand-swapped MFMA -> coalesced Vt[b][d][t] stores.
// Grid: x=N/256, y=M/128, z=batch; nwg % 8 == 0. K % 64 == 0, K >= 96.
// ---------------------------------------------------------------------------
template<typename OutT, int MODE, bool HAS_BIAS>
__global__ __launch_bounds__(256, 1) void gemm4w(
    const u16* __restrict__ A, size_t sA, int ldaB,
    const u16* __restrict__ B, size_t sB, int ldbB,
    OutT* __restrict__ C, size_t sC, int ldc,
    const float* __restrict__ bias, float scale, int K,
    u16* __restrict__ out2, u16* __restrict__ out3)
{
  constexpr int SLOT_A = 128 * 32;          // 4096 elems (8 KB)
  constexpr int SLOT_B = 256 * 32;          // 8192 elems (16 KB)
  constexpr int SLOT   = SLOT_A + SLOT_B;   // 24 KB
  __shared__ u16 sm[3 * SLOT];              // 72 KB -> 2 blocks/CU

  // ---- XCD-aware block swizzle (bijective: nwg % 8 == 0)
  const int gx = gridDim.x, gy = gridDim.y;
  const int nwg = gx * gy * gridDim.z;
  const int flat = blockIdx.x + gx * (blockIdx.y + gy * blockIdx.z);
  const int swz = (flat & 7) * (nwg >> 3) + (flat >> 3);
  const int bz  = swz / (gx * gy);
  const int rem = swz - bz * (gx * gy);
  const int by  = rem / gx;
  const int bx  = rem - by * gx;
  const int blockM = by * 128, blockN = bx * 256;

  const char* Abase = (const char*)(A + (size_t)bz * sA);
  const char* Bbase = (const char*)(B + (size_t)bz * sB);

  const int tid  = threadIdx.x;               // 0..255
  const int wave = tid >> 6, lane = tid & 63; // 4 waves
  const int wrow = (wave >> 1) * 64;          // 2M
  const int wcol = (wave & 1) * 128;          // 2N

  // ---- staging coords: thread -> (row 0..63 per call, swizzled col-byte)
  const int sr  = tid >> 2;                                  // 0..63
  const int scb = ((tid & 3) * 16) ^ (((sr >> 1) & 3) << 4); // involution
  const char* gA0 = Abase + (size_t)(blockM + sr)       * ldaB + scb;
  const char* gA1 = Abase + (size_t)(blockM + sr + 64)  * ldaB + scb;
  const char* gB0 = Bbase + (size_t)(blockN + sr)       * ldbB + scb;
  const char* gB1 = Bbase + (size_t)(blockN + sr + 64)  * ldbB + scb;
  const char* gB2 = Bbase + (size_t)(blockN + sr + 128) * ldbB + scb;
  const char* gB3 = Bbase + (size_t)(blockN + sr + 192) * ldbB + scb;
  const int ldsw = wave * 512;   // wave-uniform LDS dest base (elems/call)

  // stage BK=32 step p into slot p%3 (6 loads: A x2, B x4)
  auto STAGE = [&](int p) {
    u16* S = sm + (p % 3) * SLOT;
    const int kb = p * 64;        // 32 bf16 = 64 bytes per step
    gld_lds16(gA0 + kb, S + ldsw);
    gld_lds16(gA1 + kb, S + 2048 + ldsw);
    gld_lds16(gB0 + kb, S + SLOT_A + ldsw);
    gld_lds16(gB1 + kb, S + SLOT_A + 2048 + ldsw);
    gld_lds16(gB2 + kb, S + SLOT_A + 4096 + ldsw);
    gld_lds16(gB3 + kb, S + SLOT_A + 6144 + ldsw);
  };

  // ---- precomputed swizzled frag read offsets (elems, slot-relative)
  const int r16 = lane & 15, q8 = (lane >> 4) * 8;
  int offA[4], offB[8];
#pragma unroll
  for (int mi = 0; mi < 4; ++mi) {
    const int row = wrow + mi * 16 + r16;
    offA[mi] = row * 32 + (q8 ^ (((row >> 1) & 3) << 3));
  }
#pragma unroll
  for (int nj = 0; nj < 8; ++nj) {
    const int row = wcol + nj * 16 + r16;
    offB[nj] = row * 32 + (q8 ^ (((row >> 1) & 3) << 3));
  }

  f32x4 acc[4][8] = {};
  const bool vblk = (MODE == 1) && (blockN >= 2048);

  const int NP = K >> 5;   // BK=32 phases

  // ---- prologue: stage slots 0 and 1 (12 loads)
  STAGE(0); STAGE(1);

  for (int p = 0; p < NP; ++p) {
    const u16* S  = sm + (p % 3) * SLOT;
    const u16* SB = S + SLOT_A;

    // counted wait: outstanding = slot p (6) + slot p+1 (6); vmcnt(6)
    // forces slot p, leaves the newest 6 in flight. Drain only at the end.
    if (p + 1 < NP) asm volatile("s_waitcnt vmcnt(6)" ::: "memory");
    else            asm volatile("s_waitcnt vmcnt(0)" ::: "memory");
    __builtin_amdgcn_s_barrier();
    __builtin_amdgcn_sched_barrier(0);

    short8 a[4], b[8];
#pragma unroll
    for (int nj = 0; nj < 8; ++nj) b[nj] = *(const short8*)(SB + offB[nj]);
#pragma unroll
    for (int mi = 0; mi < 4; ++mi) a[mi] = *(const short8*)(S + offA[mi]);

    if (p + 2 < NP) STAGE(p + 2);

    __builtin_amdgcn_s_setprio(1);
    if (vblk) {
#pragma unroll
      for (int mi = 0; mi < 4; ++mi)
#pragma unroll
        for (int nj = 0; nj < 8; ++nj)
          acc[mi][nj] = __builtin_amdgcn_mfma_f32_16x16x32_bf16(
              b[nj], a[mi], acc[mi][nj], 0, 0, 0);
    } else {
#pragma unroll
      for (int mi = 0; mi < 4; ++mi)
#pragma unroll
        for (int nj = 0; nj < 8; ++nj)
          acc[mi][nj] = __builtin_amdgcn_mfma_f32_16x16x32_bf16(
              a[mi], b[nj], acc[mi][nj], 0, 0, 0);
    }
    __builtin_amdgcn_s_setprio(0);
  }

  // ---- epilogue: C/D layout col=lane&15, row=(lane>>4)*4+i
  const int cr = lane & 15, rr0 = (lane >> 4) * 4;
  OutT* Cb = C + (size_t)bz * sC;
  if (vblk) {
    // operand-swapped: D[row = W-side (d)][col = X-side (t, within M)]
#pragma unroll
    for (int nj = 0; nj < 8; ++nj) {
#pragma unroll
      for (int mi = 0; mi < 4; ++mi) {
        f32x4 v = acc[mi][nj];
        const int tg = blockM + wrow + mi * 16 + cr;   // global M row
        const int b_ = tg >> 11, t0 = tg & 2047;
        const int d0 = blockN - 2048 + wcol + nj * 16 + rr0;
#pragma unroll
        for (int i = 0; i < 4; ++i) {
          const float bval = HAS_BIAS ? bias[2048 + d0 + i] : 0.0f;
          out3[((size_t)b_ * 1024 + d0 + i) * 2048 + t0] = f2bf(v[i] + bval);
        }
      }
    }
  } else {
#pragma unroll
    for (int nj = 0; nj < 8; ++nj) {
      const int colg = blockN + wcol + nj * 16 + cr;
      const float bval = HAS_BIAS ? bias[colg] : 0.0f;
#pragma unroll
      for (int mi = 0; mi < 4; ++mi) {
        f32x4 v = acc[mi][nj];
        const int rowg = blockM + wrow + mi * 16 + rr0;
        if constexpr (MODE == 0) {
#pragma unroll
          for (int i = 0; i < 4; ++i)
            store_out(&Cb[(size_t)(rowg + i) * ldc + colg], v[i] * scale + bval);
        } else {
          u16* dst = (colg < 1024) ? (u16*)Cb : out2;
          const int c2 = colg & 1023;
#pragma unroll
          for (int i = 0; i < 4; ++i)
            dst[(size_t)(rowg + i) * 1024 + c2] = f2bf(v[i] + bval);
        }
      }
    }
  }
}

// ---------------------------------------------------------------------------
// aux kernels
// ---------------------------------------------------------------------------
__global__ __launch_bounds__(256) void cvt_f32_bf16(
    const float* __restrict__ in, u16* __restrict__ out, int n4)
{
  int i = blockIdx.x * 256 + threadIdx.x;
  if (i >= n4) return;
  float4 v = ((const float4*)in)[i];
  uint2 u;
  u.x = (unsigned)f2bf(v.x) | ((unsigned)f2bf(v.y) << 16);
  u.y = (unsigned)f2bf(v.z) | ((unsigned)f2bf(v.w) << 16);
  ((uint2*)out)[i] = u;
}

__global__ __launch_bounds__(256) void transpose_cvt(
    const float* __restrict__ W, u16* __restrict__ Wt)
{
  __shared__ u16 tile[32][33];
  const int tx = threadIdx.x;
  const int ty = threadIdx.y;
  const int bx = blockIdx.x * 32;
  const int by = blockIdx.y * 32;
#pragma unroll
  for (int j = 0; j < 4; ++j) {
    int d = by + ty * 4 + j;
    tile[ty * 4 + j][tx] = f2bf(W[(size_t)d * DD + bx + tx]);
  }
  __syncthreads();
#pragma unroll
  for (int j = 0; j < 4; ++j) {
    int f = bx + ty * 4 + j;
    Wt[(size_t)f * DD + by + tx] = tile[tx][ty * 4 + j];
  }
}

__global__ __launch_bounds__(256) void concat_bias(
    const float* __restrict__ bq, const float* __restrict__ bk,
    const float* __restrict__ bv, float* __restrict__ out)
{
  int i = blockIdx.x * 256 + threadIdx.x;   // 3072 total
  const float* src = (i < 1024) ? bq : ((i < 2048) ? bk : bv);
  out[i] = src[i & 1023];
}

__global__ __launch_bounds__(256) void softmax_inplace(float* __restrict__ S)
{
  const int tid = threadIdx.x;
  float* rp = S + (size_t)blockIdx.x * SS;

  float4 v0 = ((const float4*)rp)[tid];
  float4 v1 = ((const float4*)rp)[tid + 256];

  float m = fmaxf(fmaxf(fmaxf(v0.x, v0.y), fmaxf(v0.z, v0.w)),
                  fmaxf(fmaxf(v1.x, v1.y), fmaxf(v1.z, v1.w)));
#pragma unroll
  for (int off = 32; off; off >>= 1) m = fmaxf(m, __shfl_xor(m, off));

  __shared__ float smax[4];
  __shared__ float ssum[4];
  const int wave = tid >> 6, lane = tid & 63;
  if (lane == 0) smax[wave] = m;
  __syncthreads();
  m = fmaxf(fmaxf(smax[0], smax[1]), fmaxf(smax[2], smax[3]));

  float e[8];
  e[0] = __expf(v0.x - m); e[1] = __expf(v0.y - m);
  e[2] = __expf(v0.z - m); e[3] = __expf(v0.w - m);
  e[4] = __expf(v1.x - m); e[5] = __expf(v1.y - m);
  e[6] = __expf(v1.z - m); e[7] = __expf(v1.w - m);
  float s = e[0] + e[1] + e[2] + e[3] + e[4] + e[5] + e[6] + e[7];
#pragma unroll
  for (int off = 32; off; off >>= 1) s += __shfl_xor(s, off);
  if (lane == 0) ssum[wave] = s;
  __syncthreads();
  float inv = 1.0f / (ssum[0] + ssum[1] + ssum[2] + ssum[3]);

  uint2 u0, u1;
  u0.x = (unsigned)f2bf(e[0] * inv) | ((unsigned)f2bf(e[1] * inv) << 16);
  u0.y = (unsigned)f2bf(e[2] * inv) | ((unsigned)f2bf(e[3] * inv) << 16);
  u1.x = (unsigned)f2bf(e[4] * inv) | ((unsigned)f2bf(e[5] * inv) << 16);
  u1.y = (unsigned)f2bf(e[6] * inv) | ((unsigned)f2bf(e[7] * inv) << 16);
  ((uint2*)rp)[tid]       = u0;
  ((uint2*)rp)[tid + 256] = u1;
}

// ---------------------------------------------------------------------------
extern "C" void kernel_launch(void* const* d_in, const int* in_sizes, int n_in,
                              void* d_out, int out_size, void* d_ws, size_t ws_size,
                              hipStream_t stream) {
  (void)in_sizes; (void)n_in; (void)out_size; (void)ws_size;
  const float* X  = (const float*)d_in[0];
  const float* Wq = (const float*)d_in[1];
  const float* bq = (const float*)d_in[2];
  const float* Wk = (const float*)d_in[3];
  const float* bk = (const float*)d_in[4];
  const float* Wv = (const float*)d_in[5];
  const float* bv = (const float*)d_in[6];
  const float* Wo = (const float*)d_in[7];
  const float* bo = (const float*)d_in[8];

  char* ws = (char*)d_ws;
  const size_t MBy = 1ull << 20;
  u16*   Xbf   = (u16*)(ws + 0);          // 16 MB [8192][1024]
  u16*   WtAll = (u16*)(ws + 16 * MBy);   //  6 MB [3072][1024]
  u16*   Wto   = (u16*)(ws + 22 * MBy);   //  2 MB [1024][1024]
  u16*   Qb    = (u16*)(ws + 24 * MBy);   // 16 MB [8192][1024]
  u16*   Kb    = (u16*)(ws + 40 * MBy);   // 16 MB
  u16*   Vt    = (u16*)(ws + 56 * MBy);   // 16 MB [4][1024][2048]
  float* Sf    = (float*)(ws + 72 * MBy); // 64 MB [4][2048][2048]
  float* bqkv  = (float*)(ws + 72 * MBy); // aliases Sf (consumed before QK^T)
  u16*   Ctx   = (u16*)(ws + 136 * MBy);  // 16 MB [8192][1024]

  // 1. conversions + packing
  cvt_f32_bf16<<<dim3((BB * SS * DD / 4) / 256), 256, 0, stream>>>(X, Xbf, BB * SS * DD / 4);
  dim3 tb(32, 8);
  transpose_cvt<<<dim3(32, 32), tb, 0, stream>>>(Wq, WtAll);
  transpose_cvt<<<dim3(32, 32), tb, 0, stream>>>(Wk, WtAll + 1024 * 1024);
  transpose_cvt<<<dim3(32, 32), tb, 0, stream>>>(Wv, WtAll + 2 * 1024 * 1024);
  transpose_cvt<<<dim3(32, 32), tb, 0, stream>>>(Wo, Wto);
  concat_bias<<<dim3(12), 256, 0, stream>>>(bq, bk, bv, bqkv);

  // 2. merged QKV projection: [8192][3072]; V via operand-swap (768 blocks)
  gemm4w<u16, 1, true><<<dim3(12, 64, 1), 256, 0, stream>>>(
      Xbf, 0, DD * 2, WtAll, 0, DD * 2,
      Qb, 0, 0, bqkv, 1.0f, DD, Kb, Vt);

  // 3. scores = Q K^T / 8 (fp32, 512 blocks -> 2 blocks/CU)
  gemm4w<float, 0, false><<<dim3(8, 16, BB), 256, 0, stream>>>(
      Qb, (size_t)SS * DD, DD * 2, Kb, (size_t)SS * DD, DD * 2,
      Sf, (size_t)SS * SS, SS, nullptr, 0.125f, DD, nullptr, nullptr);

  // 4. softmax rows (in-place fp32 -> bf16)
  softmax_inplace<<<dim3(BB * SS), 256, 0, stream>>>(Sf);

  // 5. ctx = P V  (P bf16 rows of 8192 B; B = Vt; 256 blocks)
  gemm4w<u16, 0, false><<<dim3(4, 16, BB), 256, 0, stream>>>(
      (const u16*)Sf, (size_t)SS * 2 * SS, 2 * SS * 2,
      Vt, (size_t)DD * SS, SS * 2,
      Ctx, (size_t)SS * DD, DD, nullptr, 1.0f, SS, nullptr, nullptr);

  // 6. out = ctx Wo^T + bo (fp32, 256 blocks)
  gemm4w<float, 0, true><<<dim3(4, 64, 1), 256, 0, stream>>>(
      Ctx, 0, DD * 2, Wto, 0, DD * 2,
      (float*)d_out, 0, DD, bo, 1.0f, DD, nullptr, nullptr);
}

// Round 13
// 196.266 us; speedup vs baseline: 1.3263x; 1.3263x over previous
//
#include <hip/hip_runtime.h>
#include <cstdint>
#include <cstddef>

typedef unsigned short u16;
typedef __attribute__((ext_vector_type(8))) short short8;
typedef __attribute__((ext_vector_type(4))) float f32x4;

#define BB 4
#define SS 2048
#define DD 1024

__device__ __forceinline__ u16 f2bf(float f) {
  union { float f; unsigned u; } x; x.f = f;
  unsigned r = x.u + 0x7FFFu + ((x.u >> 16) & 1u);
  return (u16)(r >> 16);
}

__device__ __forceinline__ void gld_lds16(const void* g, void* l) {
  __builtin_amdgcn_global_load_lds(
      (const __attribute__((address_space(1))) void*)g,
      (__attribute__((address_space(3))) void*)l, 16, 0, 0);
}

__device__ __forceinline__ void store_out(float* p, float v) { *p = v; }
__device__ __forceinline__ void store_out(u16* p, float v) { *p = f2bf(v); }

// ---------------------------------------------------------------------------
// 3-tile-ring GEMM, 128x256 tile, BK=64/tile, 8 waves (2M x 4N), per-wave
// tile 64x64, acc[4][4] = 64 AGPR-class regs (r9's proven register regime;
// VGPR_Count 88, no spill).
// ONE vmcnt + ONE barrier per K-tile(64) (r9 paid 2+2): 32 MFMA per barrier,
// k1's ds_reads overlap k0's MFMA cluster (no intervening barrier). r9 audit:
// 3225 cyc/K-tile vs ~1900 LDS-port + 310 MFMA -> ~1300 cyc sync overhead;
// halving barrier rate attacks that directly. Ring uses POINTER ROTATION
// (S0<-S1<-S2), not %3 (r11's VALUBusy 44% mistake).
// Slot = 48 KB: Ak0[0,4096) Ak1[4096,8192) Bk0[8192,16384) Bk1[16384,24576)
// elems. 3 slots = 144 KB (1 block/CU, same as r9's effective occupancy).
// Ledger: tile t staged (6 loads: STG1 3 + STG2 3) during tile t-2; at top
// of tile t outstanding = {t:6, t+1:6} = 12 -> vmcnt(6) forces t, leaves
// t+1 in flight. Never 0 mid-loop; vmcnt(0) only at t = NT-1.
// WAR: STG*(t+2) targets the t-1 buffer; all waves' t-1 reads completed
// (lgkm-drained before their MMA(t-1)) before barrier(t), which precedes
// the stage issue. Publish: vmcnt retire + barrier orders LDS visibility.
// LDS swizzle (both-sides involution, 0 conflicts): cbyte ^= ((row>>1)&3)<<4.
// MODE 0: C[row][col] = acc*scale (+bias[col]).
// MODE 1 (QKV): colg<1024 -> C (Q), <2048 -> out2 (K); V blocks
// (blockN>=2048) use operand-swapped MFMA -> coalesced Vt[b][d][t] stores.
// Grid: x=N/256, y=M/128, z=batch; nwg % 8 == 0. K % 64 == 0, K >= 128.
// ---------------------------------------------------------------------------
template<typename OutT, int MODE, bool HAS_BIAS>
__global__ __launch_bounds__(512, 1) void gemm1b(
    const u16* __restrict__ A, size_t sA, int ldaB,
    const u16* __restrict__ B, size_t sB, int ldbB,
    OutT* __restrict__ C, size_t sC, int ldc,
    const float* __restrict__ bias, float scale, int K,
    u16* __restrict__ out2, u16* __restrict__ out3)
{
  constexpr int SLOT = 24576;            // 48 KB per K-tile(64)
  __shared__ u16 sm[3 * SLOT];           // 144 KB

  // ---- XCD-aware block swizzle (bijective: nwg % 8 == 0)
  const int gx = gridDim.x, gy = gridDim.y;
  const int nwg = gx * gy * gridDim.z;
  const int flat = blockIdx.x + gx * (blockIdx.y + gy * blockIdx.z);
  const int swz = (flat & 7) * (nwg >> 3) + (flat >> 3);
  const int bz  = swz / (gx * gy);
  const int rem = swz - bz * (gx * gy);
  const int by  = rem / gx;
  const int bx  = rem - by * gx;
  const int blockM = by * 128, blockN = bx * 256;

  const char* Abase = (const char*)(A + (size_t)bz * sA);
  const char* Bbase = (const char*)(B + (size_t)bz * sB);

  const int tid  = threadIdx.x;
  const int wave = tid >> 6, lane = tid & 63;
  const int wrow = (wave >> 2) * 64;
  const int wcol = (wave & 3) * 64;

  // ---- staging coords: thread -> (row 0..127, swizzled col-byte)
  const int sr  = tid >> 2;
  const int scb = ((tid & 3) * 16) ^ (((sr >> 1) & 3) << 4);
  const char* gA0 = Abase + (size_t)(blockM + sr)       * ldaB + scb;
  const char* gB0 = Bbase + (size_t)(blockN + sr)       * ldbB + scb;
  const char* gB1 = Bbase + (size_t)(blockN + sr + 128) * ldbB + scb;
  const int ldsw = wave * 512;   // wave-uniform LDS dest base (elems)

  // stage tile t1 into slot S: first 3 loads (Ak0, Ak1, Bk0-lo)
  auto STG1 = [&](u16* S, int t1) {
    const int kb = t1 * 128;          // 64 bf16 = 128 bytes per K-tile
    gld_lds16(gA0 + kb,      S + ldsw);              // A k0
    gld_lds16(gA0 + kb + 64, S + 4096 + ldsw);       // A k1
    gld_lds16(gB0 + kb,      S + 8192 + ldsw);       // B k0 rows 0-127
  };
  // last 3 loads (Bk0-hi, Bk1-lo, Bk1-hi)
  auto STG2 = [&](u16* S, int t1) {
    const int kb = t1 * 128;
    gld_lds16(gB1 + kb,      S + 12288 + ldsw);      // B k0 rows 128-255
    gld_lds16(gB0 + kb + 64, S + 16384 + ldsw);      // B k1 rows 0-127
    gld_lds16(gB1 + kb + 64, S + 20480 + ldsw);      // B k1 rows 128-255
  };

  // ---- precomputed swizzled frag read offsets (elems, panel-relative)
  const int r16 = lane & 15, q8 = (lane >> 4) * 8;
  int offA[4], offB[4];
#pragma unroll
  for (int mi = 0; mi < 4; ++mi) {
    const int row = wrow + mi * 16 + r16;
    offA[mi] = row * 32 + (q8 ^ (((row >> 1) & 3) << 3));
  }
#pragma unroll
  for (int nj = 0; nj < 4; ++nj) {
    const int row = wcol + nj * 16 + r16;
    offB[nj] = row * 32 + (q8 ^ (((row >> 1) & 3) << 3));
  }

  f32x4 acc[4][4] = {};
  const bool vblk = (MODE == 1) && (blockN >= 2048);

  auto MMA = [&](short8* a2, short8* b2) {
    __builtin_amdgcn_s_setprio(1);
    if (vblk) {
#pragma unroll
      for (int mi = 0; mi < 4; ++mi)
#pragma unroll
        for (int nj = 0; nj < 4; ++nj)
          acc[mi][nj] = __builtin_amdgcn_mfma_f32_16x16x32_bf16(
              b2[nj], a2[mi], acc[mi][nj], 0, 0, 0);
    } else {
#pragma unroll
      for (int mi = 0; mi < 4; ++mi)
#pragma unroll
        for (int nj = 0; nj < 4; ++nj)
          acc[mi][nj] = __builtin_amdgcn_mfma_f32_16x16x32_bf16(
              a2[mi], b2[nj], acc[mi][nj], 0, 0, 0);
    }
    __builtin_amdgcn_s_setprio(0);
  };

  const int NT = K >> 6;   // K-tiles (BK=64)

  u16* S0 = sm;
  u16* S1 = sm + SLOT;
  u16* S2 = sm + 2 * SLOT;

  // ---- prologue: stage tiles 0 and 1 (12 loads, ledger order)
  STG1(S0, 0); STG2(S0, 0);
  STG1(S1, 1); STG2(S1, 1);

  short8 a[4], b[4];
  for (int t = 0; t < NT; ++t) {
    // one counted wait + one barrier per K-tile(64)
    if (t + 1 < NT) asm volatile("s_waitcnt vmcnt(6)" ::: "memory");
    else            asm volatile("s_waitcnt vmcnt(0)" ::: "memory");
    __builtin_amdgcn_s_barrier();
    __builtin_amdgcn_sched_barrier(0);

    const bool more = (t + 2 < NT);

    // ---- k0 half
#pragma unroll
    for (int nj = 0; nj < 4; ++nj) b[nj] = *(const short8*)(S0 + 8192 + offB[nj]);
#pragma unroll
    for (int mi = 0; mi < 4; ++mi) a[mi] = *(const short8*)(S0 + offA[mi]);
    if (more) STG1(S2, t + 2);
    MMA(a, b);

    // ---- k1 half (no barrier; reads overlap k0's MFMA cluster)
#pragma unroll
    for (int nj = 0; nj < 4; ++nj) b[nj] = *(const short8*)(S0 + 16384 + offB[nj]);
#pragma unroll
    for (int mi = 0; mi < 4; ++mi) a[mi] = *(const short8*)(S0 + 4096 + offA[mi]);
    if (more) STG2(S2, t + 2);
    MMA(a, b);

    // rotate ring
    u16* tmp = S0; S0 = S1; S1 = S2; S2 = tmp;
  }

  // ---- epilogue: C/D layout col=lane&15, row=(lane>>4)*4+i
  const int cr = lane & 15, rr0 = (lane >> 4) * 4;
  OutT* Cb = C + (size_t)bz * sC;
  if (vblk) {
    // operand-swapped: D[row = W-side (d)][col = X-side (t, within M)]
#pragma unroll
    for (int nj = 0; nj < 4; ++nj) {
#pragma unroll
      for (int mi = 0; mi < 4; ++mi) {
        f32x4 v = acc[mi][nj];
        const int tg = blockM + wrow + mi * 16 + cr;   // global M row
        const int b_ = tg >> 11, t0 = tg & 2047;
        const int d0 = blockN - 2048 + wcol + nj * 16 + rr0;
#pragma unroll
        for (int i = 0; i < 4; ++i) {
          const float bval = HAS_BIAS ? bias[2048 + d0 + i] : 0.0f;
          out3[((size_t)b_ * 1024 + d0 + i) * 2048 + t0] = f2bf(v[i] + bval);
        }
      }
    }
  } else {
#pragma unroll
    for (int nj = 0; nj < 4; ++nj) {
      const int colg = blockN + wcol + nj * 16 + cr;
      const float bval = HAS_BIAS ? bias[colg] : 0.0f;
#pragma unroll
      for (int mi = 0; mi < 4; ++mi) {
        f32x4 v = acc[mi][nj];
        const int rowg = blockM + wrow + mi * 16 + rr0;
        if constexpr (MODE == 0) {
#pragma unroll
          for (int i = 0; i < 4; ++i)
            store_out(&Cb[(size_t)(rowg + i) * ldc + colg], v[i] * scale + bval);
        } else {
          u16* dst = (colg < 1024) ? (u16*)Cb : out2;
          const int c2 = colg & 1023;
#pragma unroll
          for (int i = 0; i < 4; ++i)
            dst[(size_t)(rowg + i) * 1024 + c2] = f2bf(v[i] + bval);
        }
      }
    }
  }
}

// ---------------------------------------------------------------------------
// aux kernels
// ---------------------------------------------------------------------------
__global__ __launch_bounds__(256) void cvt_f32_bf16(
    const float* __restrict__ in, u16* __restrict__ out, int n4)
{
  int i = blockIdx.x * 256 + threadIdx.x;
  if (i >= n4) return;
  float4 v = ((const float4*)in)[i];
  uint2 u;
  u.x = (unsigned)f2bf(v.x) | ((unsigned)f2bf(v.y) << 16);
  u.y = (unsigned)f2bf(v.z) | ((unsigned)f2bf(v.w) << 16);
  ((uint2*)out)[i] = u;
}

__global__ __launch_bounds__(256) void transpose_cvt(
    const float* __restrict__ W, u16* __restrict__ Wt)
{
  __shared__ u16 tile[32][33];
  const int tx = threadIdx.x;
  const int ty = threadIdx.y;
  const int bx = blockIdx.x * 32;
  const int by = blockIdx.y * 32;
#pragma unroll
  for (int j = 0; j < 4; ++j) {
    int d = by + ty * 4 + j;
    tile[ty * 4 + j][tx] = f2bf(W[(size_t)d * DD + bx + tx]);
  }
  __syncthreads();
#pragma unroll
  for (int j = 0; j < 4; ++j) {
    int f = bx + ty * 4 + j;
    Wt[(size_t)f * DD + by + tx] = tile[tx][ty * 4 + j];
  }
}

__global__ __launch_bounds__(256) void concat_bias(
    const float* __restrict__ bq, const float* __restrict__ bk,
    const float* __restrict__ bv, float* __restrict__ out)
{
  int i = blockIdx.x * 256 + threadIdx.x;   // 3072 total
  const float* src = (i < 1024) ? bq : ((i < 2048) ? bk : bv);
  out[i] = src[i & 1023];
}

__global__ __launch_bounds__(256) void softmax_inplace(float* __restrict__ S)
{
  const int tid = threadIdx.x;
  float* rp = S + (size_t)blockIdx.x * SS;

  float4 v0 = ((const float4*)rp)[tid];
  float4 v1 = ((const float4*)rp)[tid + 256];

  float m = fmaxf(fmaxf(fmaxf(v0.x, v0.y), fmaxf(v0.z, v0.w)),
                  fmaxf(fmaxf(v1.x, v1.y), fmaxf(v1.z, v1.w)));
#pragma unroll
  for (int off = 32; off; off >>= 1) m = fmaxf(m, __shfl_xor(m, off));

  __shared__ float smax[4];
  __shared__ float ssum[4];
  const int wave = tid >> 6, lane = tid & 63;
  if (lane == 0) smax[wave] = m;
  __syncthreads();
  m = fmaxf(fmaxf(smax[0], smax[1]), fmaxf(smax[2], smax[3]));

  float e[8];
  e[0] = __expf(v0.x - m); e[1] = __expf(v0.y - m);
  e[2] = __expf(v0.z - m); e[3] = __expf(v0.w - m);
  e[4] = __expf(v1.x - m); e[5] = __expf(v1.y - m);
  e[6] = __expf(v1.z - m); e[7] = __expf(v1.w - m);
  float s = e[0] + e[1] + e[2] + e[3] + e[4] + e[5] + e[6] + e[7];
#pragma unroll
  for (int off = 32; off; off >>= 1) s += __shfl_xor(s, off);
  if (lane == 0) ssum[wave] = s;
  __syncthreads();
  float inv = 1.0f / (ssum[0] + ssum[1] + ssum[2] + ssum[3]);

  uint2 u0, u1;
  u0.x = (unsigned)f2bf(e[0] * inv) | ((unsigned)f2bf(e[1] * inv) << 16);
  u0.y = (unsigned)f2bf(e[2] * inv) | ((unsigned)f2bf(e[3] * inv) << 16);
  u1.x = (unsigned)f2bf(e[4] * inv) | ((unsigned)f2bf(e[5] * inv) << 16);
  u1.y = (unsigned)f2bf(e[6] * inv) | ((unsigned)f2bf(e[7] * inv) << 16);
  ((uint2*)rp)[tid]       = u0;
  ((uint2*)rp)[tid + 256] = u1;
}

// ---------------------------------------------------------------------------
extern "C" void kernel_launch(void* const* d_in, const int* in_sizes, int n_in,
                              void* d_out, int out_size, void* d_ws, size_t ws_size,
                              hipStream_t stream) {
  (void)in_sizes; (void)n_in; (void)out_size; (void)ws_size;
  const float* X  = (const float*)d_in[0];
  const float* Wq = (const float*)d_in[1];
  const float* bq = (const float*)d_in[2];
  const float* Wk = (const float*)d_in[3];
  const float* bk = (const float*)d_in[4];
  const float* Wv = (const float*)d_in[5];
  const float* bv = (const float*)d_in[6];
  const float* Wo = (const float*)d_in[7];
  const float* bo = (const float*)d_in[8];

  char* ws = (char*)d_ws;
  const size_t MBy = 1ull << 20;
  u16*   Xbf   = (u16*)(ws + 0);          // 16 MB [8192][1024]
  u16*   WtAll = (u16*)(ws + 16 * MBy);   //  6 MB [3072][1024]
  u16*   Wto   = (u16*)(ws + 22 * MBy);   //  2 MB [1024][1024]
  u16*   Qb    = (u16*)(ws + 24 * MBy);   // 16 MB [8192][1024]
  u16*   Kb    = (u16*)(ws + 40 * MBy);   // 16 MB
  u16*   Vt    = (u16*)(ws + 56 * MBy);   // 16 MB [4][1024][2048]
  float* Sf    = (float*)(ws + 72 * MBy); // 64 MB [4][2048][2048]
  float* bqkv  = (float*)(ws + 72 * MBy); // aliases Sf (consumed before QK^T)
  u16*   Ctx   = (u16*)(ws + 136 * MBy);  // 16 MB [8192][1024]

  // 1. conversions + packing
  cvt_f32_bf16<<<dim3((BB * SS * DD / 4) / 256), 256, 0, stream>>>(X, Xbf, BB * SS * DD / 4);
  dim3 tb(32, 8);
  transpose_cvt<<<dim3(32, 32), tb, 0, stream>>>(Wq, WtAll);
  transpose_cvt<<<dim3(32, 32), tb, 0, stream>>>(Wk, WtAll + 1024 * 1024);
  transpose_cvt<<<dim3(32, 32), tb, 0, stream>>>(Wv, WtAll + 2 * 1024 * 1024);
  transpose_cvt<<<dim3(32, 32), tb, 0, stream>>>(Wo, Wto);
  concat_bias<<<dim3(12), 256, 0, stream>>>(bq, bk, bv, bqkv);

  // 2. merged QKV projection: [8192][3072]; V via operand-swap (768 blocks)
  gemm1b<u16, 1, true><<<dim3(12, 64, 1), 512, 0, stream>>>(
      Xbf, 0, DD * 2, WtAll, 0, DD * 2,
      Qb, 0, 0, bqkv, 1.0f, DD, Kb, Vt);

  // 3. scores = Q K^T / 8 (fp32, 512 blocks)
  gemm1b<float, 0, false><<<dim3(8, 16, BB), 512, 0, stream>>>(
      Qb, (size_t)SS * DD, DD * 2, Kb, (size_t)SS * DD, DD * 2,
      Sf, (size_t)SS * SS, SS, nullptr, 0.125f, DD, nullptr, nullptr);

  // 4. softmax rows (in-place fp32 -> bf16)
  softmax_inplace<<<dim3(BB * SS), 256, 0, stream>>>(Sf);

  // 5. ctx = P V  (P bf16 rows of 8192 B; B = Vt; 256 blocks)
  gemm1b<u16, 0, false><<<dim3(4, 16, BB), 512, 0, stream>>>(
      (const u16*)Sf, (size_t)SS * 2 * SS, 2 * SS * 2,
      Vt, (size_t)DD * SS, SS * 2,
      Ctx, (size_t)SS * DD, DD, nullptr, 1.0f, SS, nullptr, nullptr);

  // 6. out = ctx Wo^T + bo (fp32, 256 blocks)
  gemm1b<float, 0, true><<<dim3(4, 64, 1), 512, 0, stream>>>(
      Ctx, 0, DD * 2, Wto, 0, DD * 2,
      (float*)d_out, 0, DD, bo, 1.0f, DD, nullptr, nullptr);
}